// Round 1
// baseline (48.661 us; speedup 1.0000x reference)
//
#include <hip/hip_runtime.h>
#include <math.h>

// out[m] = s*(1-s) * (W[m,:] @ (x_f - x_i)),  s = sigmoid(W[m,:] @ x_i + b[m])
// D = M = 8192, W fp32 row-major. Strictly HBM-bound on the single pass over W.

constexpr int D_DIM = 8192;
constexpr int BLOCK = 1024;           // 16 waves
constexpr int ROWS_PER_BLOCK = 16;    // one row per wave

__global__ __launch_bounds__(BLOCK)
void dyn_fused_kernel(const float* __restrict__ x_i,
                      const float* __restrict__ x_f,
                      const float* __restrict__ W,
                      const float* __restrict__ b,
                      float* __restrict__ out,
                      int M)
{
    __shared__ float s_xi[D_DIM];   // 32 KiB
    __shared__ float s_v[D_DIM];    // 32 KiB

    const int tid = threadIdx.x;
    constexpr int NCHUNK = D_DIM / 4;   // 2048 float4 per vector

    // Stage x_i and v = x_f - x_i into LDS (each thread: 2 float4 of each).
    const float4* xi_g = reinterpret_cast<const float4*>(x_i);
    const float4* xf_g = reinterpret_cast<const float4*>(x_f);
    float4* sxi_w = reinterpret_cast<float4*>(s_xi);
    float4* sv_w  = reinterpret_cast<float4*>(s_v);
    #pragma unroll
    for (int c = tid; c < NCHUNK; c += BLOCK) {
        float4 a = xi_g[c];
        float4 f = xf_g[c];
        sxi_w[c] = a;
        sv_w[c]  = make_float4(f.x - a.x, f.y - a.y, f.z - a.z, f.w - a.w);
    }
    __syncthreads();

    const int wave = tid >> 6;
    const int lane = tid & 63;
    const int row  = blockIdx.x * ROWS_PER_BLOCK + wave;
    if (row >= M) return;

    const float4* Wr  = reinterpret_cast<const float4*>(W + (size_t)row * D_DIM);
    const float4* sxi = reinterpret_cast<const float4*>(s_xi);
    const float4* sv  = reinterpret_cast<const float4*>(s_v);

    float acc_i = 0.0f;   // W[m]·x_i
    float acc_v = 0.0f;   // W[m]·v
    #pragma unroll 4
    for (int c = lane; c < NCHUNK; c += 64) {
        float4 w  = Wr[c];     // coalesced 1 KiB per wave instruction
        float4 xi = sxi[c];    // conflict-free ds_read_b128
        float4 vv = sv[c];
        acc_i = fmaf(w.x, xi.x, acc_i);
        acc_i = fmaf(w.y, xi.y, acc_i);
        acc_i = fmaf(w.z, xi.z, acc_i);
        acc_i = fmaf(w.w, xi.w, acc_i);
        acc_v = fmaf(w.x, vv.x, acc_v);
        acc_v = fmaf(w.y, vv.y, acc_v);
        acc_v = fmaf(w.z, vv.z, acc_v);
        acc_v = fmaf(w.w, vv.w, acc_v);
    }

    // 64-lane butterfly reduction of both accumulators.
    #pragma unroll
    for (int off = 32; off > 0; off >>= 1) {
        acc_i += __shfl_down(acc_i, off, 64);
        acc_v += __shfl_down(acc_v, off, 64);
    }

    if (lane == 0) {
        float z = acc_i + b[row];
        float s = 1.0f / (1.0f + expf(-z));
        out[row] = s * (1.0f - s) * acc_v;
    }
}

extern "C" void kernel_launch(void* const* d_in, const int* in_sizes, int n_in,
                              void* d_out, int out_size, void* d_ws, size_t ws_size,
                              hipStream_t stream) {
    // setup_inputs order: t(1), y(M), x_i(D), x_f(D), W(M*D), b(M)
    const float* x_i = (const float*)d_in[2];
    const float* x_f = (const float*)d_in[3];
    const float* W   = (const float*)d_in[4];
    const float* b   = (const float*)d_in[5];
    float* out = (float*)d_out;
    const int M = out_size;   // 8192

    const int grid = (M + ROWS_PER_BLOCK - 1) / ROWS_PER_BLOCK;  // 512
    dyn_fused_kernel<<<grid, BLOCK, 0, stream>>>(x_i, x_f, W, b, out, M);
}